// Round 5
// baseline (6454.823 us; speedup 1.0000x reference)
//
#include <hip/hip_runtime.h>
#include <math.h>

// Problem constants
#define K_CODES 1024
#define DIM 256
#define BB 32
#define TT 2048
#define NROWS (BB * TT)            // 65536
#define QN (BB * DIM * TT)         // 16777216
#define LOSS_OFF QN
#define IDX_OFF (QN + 1)

// ws layout (in floats)
#define WS_E2 0
#define WS_SX 1024
#define WS_LOSS (1024 + NROWS)     // 66560
#define WS_BEST (WS_LOSS + 2)      // 66562; u64[NROWS] = 2*NROWS floats
#define WS_CNT (WS_BEST + 2 * NROWS)  // 197634; int[513]: 512 rowTile arrivals + 1 done2

// numpy pairwise_sum replica for 256 elements of squares.
__device__ __forceinline__ float pw128_sq(const float* p, int stride) {
    float r[8];
#pragma unroll
    for (int j = 0; j < 8; ++j) {
        float v = p[j * stride];
        r[j] = __fmul_rn(v, v);
    }
#pragma unroll
    for (int i = 8; i < 128; i += 8) {
#pragma unroll
        for (int j = 0; j < 8; ++j) {
            float v = p[(i + j) * stride];
            r[j] = __fadd_rn(r[j], __fmul_rn(v, v));
        }
    }
    return __fadd_rn(__fadd_rn(__fadd_rn(r[0], r[1]), __fadd_rn(r[2], r[3])),
                     __fadd_rn(__fadd_rn(r[4], r[5]), __fadd_rn(r[6], r[7])));
}

__device__ __forceinline__ float pw256_sq(const float* p, int stride) {
    return __fadd_rn(pw128_sq(p, stride), pw128_sq(p + 128 * stride, stride));
}

// Kernel 1a: codebook norms + zero loss accumulator + zero arrival counters.
__global__ void k_prep_e2(const float* __restrict__ emb, float* __restrict__ ws) {
    int k = blockIdx.x * 256 + threadIdx.x;
    if (k == 0) ws[WS_LOSS] = 0.0f;
    if (k < 513) ((int*)(ws + WS_CNT))[k] = 0;
    if (k < K_CODES) ws[WS_E2 + k] = pw256_sq(emb + (size_t)k * DIM, 1);
}

// Kernel 1b: per-row squared norms of x + init the argmin keys.
__global__ void k_prep_sx(const float* __restrict__ in, float* __restrict__ ws) {
    int row = blockIdx.x * 256 + threadIdx.x;
    int b = row >> 11;
    int t = row & (TT - 1);
    ws[WS_SX + row] = pw256_sq(in + (size_t)b * (DIM * TT) + t, TT);
    ((unsigned long long*)(ws + WS_BEST))[row] = 0xFFFFFFFFFFFFFFFFull;
}

// Kernel 2: distance GEMM + argmin + fused epilogue.
// Grid 1024: bid = (rowTile<<1)|codeHalf. Each block: 128 rows x 512 codes.
// Pipelined double-buffered LDS (64KB), one barrier per stage; loads for stage
// s+1 issue into regs right after the barrier and their latency hides under the
// 512-fma compute of stage s. Wave-internal 8x8 (tx,ty) mapping makes both
// xv and ev ds_read_b128 conflict-free (8 unique addrs on 8 distinct bank
// groups). The (tx,ty)<->(row,code) relation and every fma chain are unchanged
// vs R2 -> bit-identical distances/indices.
// Epilogue fused via last-arriver counters: the 2nd block of each rowTile pair
// does gather+transpose+loss; the 512th finisher finalizes the loss.
// NOTE: launch_bounds min-waves/EU stays 2 (4 forces a 64-VGPR cap + spills, R1).
__launch_bounds__(256, 2)
__global__ void k_main(const float* __restrict__ in, const float* __restrict__ emb,
                       const float* __restrict__ ws,
                       unsigned long long* __restrict__ best,
                       int* __restrict__ cnt, float* __restrict__ wloss,
                       float* __restrict__ out) {
    __shared__ float smem[16384];      // 64KB: buf0 = xs|es, buf1 = xs|es (8192 floats each)

    const int tid = threadIdx.x;
    // 8x8 wave-internal logical mapping: each wave spans 8 tx x 8 ty.
    const int tx = ((tid >> 6) & 1) * 8 + (tid & 7);
    const int ty = ((tid >> 7) & 1) * 8 + ((tid >> 3) & 7);
    const int rowTile = blockIdx.x >> 1;
    const int ch = blockIdx.x & 1;       // code half: codes [ch*512, ch*512+512)
    const int row0 = rowTile * 128;
    const int b = row0 >> 11;            // row0 / 2048
    const int t0 = row0 & (TT - 1);
    const float* xbase = in + (size_t)b * (DIM * TT) + t0;   // + d*TT + r

    // preload row norms for my 8 rows
    float sxr[8];
#pragma unroll
    for (int i = 0; i < 8; ++i) sxr[i] = ws[WS_SX + row0 + 8 * ty + i];

    float bestd[8];
    int bestidx[8];
#pragma unroll
    for (int i = 0; i < 8; ++i) { bestd[i] = INFINITY; bestidx[i] = 0; }

    // x-stage lane mapping (consecutive-8-lane groups span rows 8 apart ->
    // conflict-free swizzled ds_write_b128; global address set per instr is
    // still 64 consecutive floats -> coalesced).
    const int lr = ((tid & 7) << 3) | ((tid >> 3) & 7) | (tid & 64);
    const int lh = tid >> 7;    // x-load half (c4 parity)

    float xr[4][4];             // staged x regs [it][k], static indexing only
    float4 er[4];               // staged e regs

    // ---- prologue: load + write stage 0 into buf0 ----
    {
#pragma unroll
        for (int it = 0; it < 4; ++it) {
            int c4 = lh + 2 * it;
#pragma unroll
            for (int k = 0; k < 4; ++k)
                xr[it][k] = xbase[(size_t)(4 * c4 + k) * TT + lr];
        }
        const int cb = ch * 512;
#pragma unroll
        for (int it = 0; it < 4; ++it) {
            int s2 = tid + 256 * it;
            er[it] = *(const float4*)&emb[(size_t)(cb + (s2 >> 3)) * DIM + (s2 & 7) * 4];
        }
        float* xs = smem;
        float* es = smem + 4096;
#pragma unroll
        for (int it = 0; it < 4; ++it) {
            int c4 = lh + 2 * it;
            int cs = c4 ^ ((lr >> 3) & 7);
            *(float4*)&xs[lr * 32 + cs * 4] = make_float4(xr[it][0], xr[it][1], xr[it][2], xr[it][3]);
        }
#pragma unroll
        for (int it = 0; it < 4; ++it) {
            int s2 = tid + 256 * it;
            int code = s2 >> 3, c4 = s2 & 7;
            int cs = c4 ^ ((code >> 3) & 7);
            *(float4*)&es[code * 32 + cs * 4] = er[it];
        }
    }

    float acc[8][8];

    // ---- pipelined main loop: 32 stages (cc = s>>3, dc = s&7) ----
    for (int s = 0; s < 32; ++s) {
        __syncthreads();                       // buf[s&1] writes visible; buf[(s+1)&1] reads done
        float* xs = smem + (s & 1) * 8192;
        float* es = xs + 4096;

        // issue next-stage global loads (latency hides under compute below)
        if (s < 31) {
            const int sn = s + 1;
            const int d0 = (sn & 7) * 32;
#pragma unroll
            for (int it = 0; it < 4; ++it) {
                int c4 = lh + 2 * it;
#pragma unroll
                for (int k = 0; k < 4; ++k)
                    xr[it][k] = xbase[(size_t)(d0 + 4 * c4 + k) * TT + lr];
            }
            const int cb = ch * 512 + (sn >> 3) * 128;
#pragma unroll
            for (int it = 0; it < 4; ++it) {
                int s2 = tid + 256 * it;
                er[it] = *(const float4*)&emb[(size_t)(cb + (s2 >> 3)) * DIM + d0 + (s2 & 7) * 4];
            }
        }

        if ((s & 7) == 0) {
#pragma unroll
            for (int i = 0; i < 8; ++i)
#pragma unroll
                for (int j = 0; j < 8; ++j) acc[i][j] = 0.0f;
        }

        // compute from buf[s&1]: strict ascending-d fma chain per (row, code)
#pragma unroll
        for (int c4 = 0; c4 < 8; ++c4) {
            float4 xv[8], ev[8];
            const int xc = (c4 ^ (ty & 7)) * 4;
            const int ec = (c4 ^ (tx & 7)) * 4;
#pragma unroll
            for (int i = 0; i < 8; ++i) xv[i] = *(const float4*)&xs[(8 * ty + i) * 32 + xc];
#pragma unroll
            for (int j = 0; j < 8; ++j) ev[j] = *(const float4*)&es[(8 * tx + j) * 32 + ec];
#pragma unroll
            for (int i = 0; i < 8; ++i)
#pragma unroll
                for (int j = 0; j < 8; ++j) {
                    float a = acc[i][j];
                    a = __fmaf_rn(xv[i].x, ev[j].x, a);
                    a = __fmaf_rn(xv[i].y, ev[j].y, a);
                    a = __fmaf_rn(xv[i].z, ev[j].z, a);
                    a = __fmaf_rn(xv[i].w, ev[j].w, a);
                    acc[i][j] = a;
                }
        }

        // write next stage into buf[(s+1)&1] (its last readers finished at s-1,
        // guaranteed by the barrier at the top of this iteration)
        if (s < 31) {
            float* xs2 = smem + ((s + 1) & 1) * 8192;
            float* es2 = xs2 + 4096;
#pragma unroll
            for (int it = 0; it < 4; ++it) {
                int c4 = lh + 2 * it;
                int cs = c4 ^ ((lr >> 3) & 7);
                *(float4*)&xs2[lr * 32 + cs * 4] = make_float4(xr[it][0], xr[it][1], xr[it][2], xr[it][3]);
            }
#pragma unroll
            for (int it = 0; it < 4; ++it) {
                int s2 = tid + 256 * it;
                int code = s2 >> 3, c4 = s2 & 7;
                int cs = c4 ^ ((code >> 3) & 7);
                *(float4*)&es2[code * 32 + cs * 4] = er[it];
            }
        }

        // distances at end of each code chunk: dist = fl(fl(sx+e2) - fl(2*dot));
        // ascending-code scan with strict < keeps lowest index on ties.
        if ((s & 7) == 7) {
            const int cbase = ch * 512 + (s >> 3) * 128;
#pragma unroll
            for (int j = 0; j < 8; ++j) {
                const int code = cbase + 8 * tx + j;
                const float e2 = ws[WS_E2 + code];
#pragma unroll
                for (int i = 0; i < 8; ++i) {
                    float dist = __fsub_rn(__fadd_rn(sxr[i], e2), __fmul_rn(2.0f, acc[i][j]));
                    if (dist < bestd[i]) { bestd[i] = dist; bestidx[i] = code; }
                }
            }
        }
    }

    // Cross-thread argmin reduction (16 candidates per row), lexicographic
    // (dist, idx), then exact cross-block combine via u64 atomicMin
    // (dist >= ~130 > 0, so IEEE bit order == numeric order).
    __syncthreads();
    float* rd = smem;                   // [128][16]
    int* ri = (int*)(smem + 2048);      // [128][16]
#pragma unroll
    for (int i = 0; i < 8; ++i) {
        rd[(8 * ty + i) * 16 + tx] = bestd[i];
        ri[(8 * ty + i) * 16 + tx] = bestidx[i];
    }
    __syncthreads();
    if (tid < 128) {
        float bd = rd[tid * 16];
        int bi = ri[tid * 16];
#pragma unroll
        for (int x = 1; x < 16; ++x) {
            float d = rd[tid * 16 + x];
            int ix = ri[tid * 16 + x];
            if (d < bd || (d == bd && ix < bi)) { bd = d; bi = ix; }
        }
        unsigned long long key =
            ((unsigned long long)__float_as_uint(bd) << 32) | (unsigned int)bi;
        atomicMin(&best[row0 + tid], key);
    }

    // ---- last-arriver fused epilogue ----
    // All threads fence their own prior (atomic) writes, sync, then one thread
    // claims the arrival ticket (blessed threadfence-reduction pattern).
    __threadfence();
    __syncthreads();
    int* sflag = (int*)(smem + 5000);   // scratch word, clear of q/idx regions
    if (tid == 0) {
        int old = __hip_atomic_fetch_add(&cnt[rowTile], 1, __ATOMIC_ACQ_REL,
                                         __HIP_MEMORY_SCOPE_AGENT);
        *sflag = old;
    }
    __syncthreads();
    if (*sflag == 0) return;            // first arriver: partner will finish
    __threadfence();                    // acquire side

    int* idx_lds = (int*)(smem + 4800); // [128]; q uses smem[0..4735]
    if (tid < 128) {
        unsigned long long v = __hip_atomic_load(&best[row0 + tid], __ATOMIC_RELAXED,
                                                 __HIP_MEMORY_SCOPE_AGENT);
        int bi = (int)(unsigned int)(v & 0xFFFFFFFFull);
        idx_lds[tid] = bi;
        out[IDX_OFF + b * TT + t0 + tid] = (float)bi;  // indices as fp32 values
    }
    __syncthreads();

    // gather(emb, idx) -> [B][D][T] + loss partials (identical structure to R0/R2)
    float lsum = 0.0f;
    float* q = smem;                    // [128][37] (pad 37 breaks bank conflicts)
    const int qr = tid >> 3;            // 0..31 (+32*it)
    const int qf = tid & 7;
    const int er_ = tid & 127;
    const int ed_ = tid >> 7;
    for (int dc = 0; dc < 8; ++dc) {
        const int d0 = dc * 32;
        __syncthreads();
#pragma unroll
        for (int it = 0; it < 4; ++it) {
            int r = qr + 32 * it;
            float4 v = *(const float4*)&emb[(size_t)idx_lds[r] * DIM + d0 + qf * 4];
            float* dst = &q[r * 37 + qf * 4];
            dst[0] = v.x; dst[1] = v.y; dst[2] = v.z; dst[3] = v.w;
        }
        __syncthreads();
#pragma unroll
        for (int k = 0; k < 16; ++k) {
            int dd = ed_ + 2 * k;
            float qq = q[er_ * 37 + dd];
            size_t gaddr = (size_t)b * (DIM * TT) + (size_t)(d0 + dd) * TT + t0 + er_;
            float xx = in[gaddr];
            out[gaddr] = qq;
            float df = __fsub_rn(qq, xx);
            lsum = __fmaf_rn(df, df, lsum);
        }
    }
    // wave reduce + one atomic per wave
#pragma unroll
    for (int off = 32; off > 0; off >>= 1) lsum += __shfl_down(lsum, off, 64);
    if ((tid & 63) == 0) atomicAdd(wloss, lsum);

    // last finisher of all 512 finalizes the loss
    __threadfence();
    __syncthreads();
    if (tid == 0) {
        int old2 = __hip_atomic_fetch_add(&cnt[512], 1, __ATOMIC_ACQ_REL,
                                          __HIP_MEMORY_SCOPE_AGENT);
        if (old2 == 511) {
            __threadfence();
            float L = __hip_atomic_load(wloss, __ATOMIC_RELAXED,
                                        __HIP_MEMORY_SCOPE_AGENT);
            out[LOSS_OFF] = 1.25f * L / 16777216.0f;
        }
    }
}

extern "C" void kernel_launch(void* const* d_in, const int* in_sizes, int n_in,
                              void* d_out, int out_size, void* d_ws, size_t ws_size,
                              hipStream_t stream) {
    const float* in = (const float*)d_in[0];
    const float* emb = (const float*)d_in[1];
    float* out = (float*)d_out;
    float* ws = (float*)d_ws;
    unsigned long long* best = (unsigned long long*)(ws + WS_BEST);
    int* cnt = (int*)(ws + WS_CNT);

    hipLaunchKernelGGL(k_prep_e2, dim3(4), dim3(256), 0, stream, emb, ws);
    hipLaunchKernelGGL(k_prep_sx, dim3(256), dim3(256), 0, stream, in, ws);
    hipLaunchKernelGGL(k_main, dim3(1024), dim3(256), 0, stream, in, emb, ws,
                       best, cnt, ws + WS_LOSS, out);
}

// Round 6
// 6235.706 us; speedup vs baseline: 1.0351x; 1.0351x over previous
//
#include <hip/hip_runtime.h>
#include <math.h>

// Problem constants
#define K_CODES 1024
#define DIM 256
#define BB 32
#define TT 2048
#define NROWS (BB * TT)            // 65536
#define QN (BB * DIM * TT)         // 16777216
#define LOSS_OFF QN
#define IDX_OFF (QN + 1)

// ws layout (in floats)
#define WS_E2 0
#define WS_SX 1024
#define WS_LOSS (1024 + NROWS)     // 66560
#define WS_BEST (WS_LOSS + 2)      // 66562; u64[NROWS] = 2*NROWS floats
#define WS_CNT (WS_BEST + 2 * NROWS)  // 197634; int[513]: 512 rowTile arrivals + 1 done2

// numpy pairwise_sum replica for 256 elements of squares.
__device__ __forceinline__ float pw128_sq(const float* p, int stride) {
    float r[8];
#pragma unroll
    for (int j = 0; j < 8; ++j) {
        float v = p[j * stride];
        r[j] = __fmul_rn(v, v);
    }
#pragma unroll
    for (int i = 8; i < 128; i += 8) {
#pragma unroll
        for (int j = 0; j < 8; ++j) {
            float v = p[(i + j) * stride];
            r[j] = __fadd_rn(r[j], __fmul_rn(v, v));
        }
    }
    return __fadd_rn(__fadd_rn(__fadd_rn(r[0], r[1]), __fadd_rn(r[2], r[3])),
                     __fadd_rn(__fadd_rn(r[4], r[5]), __fadd_rn(r[6], r[7])));
}

__device__ __forceinline__ float pw256_sq(const float* p, int stride) {
    return __fadd_rn(pw128_sq(p, stride), pw128_sq(p + 128 * stride, stride));
}

// async global->LDS 16B copy; LDS dest is wave-uniform base + lane*16.
__device__ __forceinline__ void gload_lds16(const float* g, float* l) {
    __builtin_amdgcn_global_load_lds(
        (const __attribute__((address_space(1))) void*)g,
        (__attribute__((address_space(3))) void*)l, 16, 0, 0);
}

// Kernel 1a: codebook norms + zero loss accumulator + zero arrival counters.
__global__ void k_prep_e2(const float* __restrict__ emb, float* __restrict__ ws) {
    int k = blockIdx.x * 256 + threadIdx.x;
    if (k == 0) ws[WS_LOSS] = 0.0f;
    if (k < 513) ((int*)(ws + WS_CNT))[k] = 0;
    if (k < K_CODES) ws[WS_E2 + k] = pw256_sq(emb + (size_t)k * DIM, 1);
}

// Kernel 1b: per-row squared norms of x + init the argmin keys.
__global__ void k_prep_sx(const float* __restrict__ in, float* __restrict__ ws) {
    int row = blockIdx.x * 256 + threadIdx.x;
    int b = row >> 11;
    int t = row & (TT - 1);
    ws[WS_SX + row] = pw256_sq(in + (size_t)b * (DIM * TT) + t, TT);
    ((unsigned long long*)(ws + WS_BEST))[row] = 0xFFFFFFFFFFFFFFFFull;
}

// Kernel 2: distance GEMM + argmin + fused epilogue.
// Grid 1024: bid = (rowTile<<1)|codeHalf. Each block: 128 rows x 512 codes.
// Pipelined double-buffered LDS (64KB), one barrier per stage. E-tile staged
// via async global_load_lds with PRE-SWIZZLED per-lane global source (LDS dest
// linear: slot s2 -> float offset s2*4 == code*32 + cs_lin*4; source chunk
// c4 = cs_lin ^ ((code>>3)&7)), so LDS contents are byte-identical to the
// ds_write version -> compute bit-identical. X-tile reg-staged + swizzled
// ds_write (transpose, can't use gload_lds). __syncthreads() drains vmcnt so
// async loads are complete at each stage top.
// OCCUPANCY PIN: amdgpu_waves_per_eu(2,2). LDS 64KB caps us at 2 blocks/CU
// (= 2 waves/EU) regardless; max=2 stops the allocator from targeting 4
// waves/EU at 128 VGPRs and spilling acc to scratch (R5: VGPR=128,
// WRITE_SIZE 12.4GB of spill traffic, 10x slowdown). Budget is now 256.
__attribute__((amdgpu_flat_work_group_size(256, 256)))
__attribute__((amdgpu_waves_per_eu(2, 2)))
__global__ void k_main(const float* __restrict__ in, const float* __restrict__ emb,
                       const float* __restrict__ ws,
                       unsigned long long* __restrict__ best,
                       int* __restrict__ cnt, float* __restrict__ wloss,
                       float* __restrict__ out) {
    __shared__ float smem[16384];      // 64KB: buf0 = xs|es, buf1 = xs|es (8192 floats each)

    const int tid = threadIdx.x;
    // 8x8 wave-internal logical mapping: each wave spans 8 tx x 8 ty.
    const int tx = ((tid >> 6) & 1) * 8 + (tid & 7);
    const int ty = ((tid >> 7) & 1) * 8 + ((tid >> 3) & 7);
    const int wv = tid >> 6;           // wave id
    const int lane = tid & 63;
    const int rowTile = blockIdx.x >> 1;
    const int ch = blockIdx.x & 1;       // code half: codes [ch*512, ch*512+512)
    const int row0 = rowTile * 128;
    const int b = row0 >> 11;            // row0 / 2048
    const int t0 = row0 & (TT - 1);
    const float* xbase = in + (size_t)b * (DIM * TT) + t0;   // + d*TT + r

    // preload row norms for my 8 rows
    float sxr[8];
#pragma unroll
    for (int i = 0; i < 8; ++i) sxr[i] = ws[WS_SX + row0 + 8 * ty + i];

    float bestd[8];
    int bestidx[8];
#pragma unroll
    for (int i = 0; i < 8; ++i) { bestd[i] = INFINITY; bestidx[i] = 0; }

    // x-stage lane mapping (consecutive-8-lane groups span rows 8 apart ->
    // conflict-free swizzled ds_write_b128; global address set per instr is
    // still 64 consecutive floats -> coalesced).
    const int lr = ((tid & 7) << 3) | ((tid >> 3) & 7) | (tid & 64);
    const int lh = tid >> 7;    // x-load half (c4 parity)

    float xr[4][4];             // staged x regs [it][k], static indexing only

    // ---- prologue: stage 0 into buf0 ----
    {
        // e: async direct-to-LDS, pre-swizzled source
        const int cb = ch * 512;
        float* es0 = smem + 4096;
#pragma unroll
        for (int it = 0; it < 4; ++it) {
            int s2 = 256 * it + 64 * wv + lane;
            int code = s2 >> 3;
            int c4s = (s2 & 7) ^ ((s2 >> 6) & 7);
            gload_lds16(&emb[(size_t)(cb + code) * DIM + c4s * 4],
                        &es0[1024 * it + 256 * wv]);
        }
        // x: reg-stage + swizzled ds_write
#pragma unroll
        for (int it = 0; it < 4; ++it) {
            int c4 = lh + 2 * it;
#pragma unroll
            for (int k = 0; k < 4; ++k)
                xr[it][k] = xbase[(size_t)(4 * c4 + k) * TT + lr];
        }
        float* xs0 = smem;
#pragma unroll
        for (int it = 0; it < 4; ++it) {
            int c4 = lh + 2 * it;
            int cs = c4 ^ ((lr >> 3) & 7);
            *(float4*)&xs0[lr * 32 + cs * 4] = make_float4(xr[it][0], xr[it][1], xr[it][2], xr[it][3]);
        }
    }

    float acc[8][8];

    // ---- pipelined main loop: 32 stages (cc = s>>3, dc = s&7) ----
    for (int s = 0; s < 32; ++s) {
        __syncthreads();   // drains vmcnt+lgkmcnt: buf[s&1] complete; buf[(s+1)&1] readers done
        float* xs = smem + (s & 1) * 8192;
        float* es = xs + 4096;

        // issue next-stage loads (latency hides under compute below)
        if (s < 31) {
            const int sn = s + 1;
            const int d0 = (sn & 7) * 32;
            // e: async direct-to-LDS into buf[(s+1)&1] (nobody reads it this stage)
            {
                const int cb = ch * 512 + (sn >> 3) * 128;
                float* es2 = smem + ((s + 1) & 1) * 8192 + 4096;
#pragma unroll
                for (int it = 0; it < 4; ++it) {
                    int s2 = 256 * it + 64 * wv + lane;
                    int code = s2 >> 3;
                    int c4s = (s2 & 7) ^ ((s2 >> 6) & 7);
                    gload_lds16(&emb[(size_t)(cb + code) * DIM + d0 + c4s * 4],
                                &es2[1024 * it + 256 * wv]);
                }
            }
            // x: reg loads (transpose gather, stride TT)
#pragma unroll
            for (int it = 0; it < 4; ++it) {
                int c4 = lh + 2 * it;
#pragma unroll
                for (int k = 0; k < 4; ++k)
                    xr[it][k] = xbase[(size_t)(d0 + 4 * c4 + k) * TT + lr];
            }
        }

        if ((s & 7) == 0) {
#pragma unroll
            for (int i = 0; i < 8; ++i)
#pragma unroll
                for (int j = 0; j < 8; ++j) acc[i][j] = 0.0f;
        }

        // compute from buf[s&1]: strict ascending-d fma chain per (row, code)
#pragma unroll
        for (int c4 = 0; c4 < 8; ++c4) {
            float4 xv[8], ev[8];
            const int xc = (c4 ^ (ty & 7)) * 4;
            const int ec = (c4 ^ (tx & 7)) * 4;
#pragma unroll
            for (int i = 0; i < 8; ++i) xv[i] = *(const float4*)&xs[(8 * ty + i) * 32 + xc];
#pragma unroll
            for (int j = 0; j < 8; ++j) ev[j] = *(const float4*)&es[(8 * tx + j) * 32 + ec];
#pragma unroll
            for (int i = 0; i < 8; ++i)
#pragma unroll
                for (int j = 0; j < 8; ++j) {
                    float a = acc[i][j];
                    a = __fmaf_rn(xv[i].x, ev[j].x, a);
                    a = __fmaf_rn(xv[i].y, ev[j].y, a);
                    a = __fmaf_rn(xv[i].z, ev[j].z, a);
                    a = __fmaf_rn(xv[i].w, ev[j].w, a);
                    acc[i][j] = a;
                }
        }

        // x write into buf[(s+1)&1] after compute
        if (s < 31) {
            float* xs2 = smem + ((s + 1) & 1) * 8192;
#pragma unroll
            for (int it = 0; it < 4; ++it) {
                int c4 = lh + 2 * it;
                int cs = c4 ^ ((lr >> 3) & 7);
                *(float4*)&xs2[lr * 32 + cs * 4] = make_float4(xr[it][0], xr[it][1], xr[it][2], xr[it][3]);
            }
        }

        // distances at end of each code chunk: dist = fl(fl(sx+e2) - fl(2*dot));
        // ascending-code scan with strict < keeps lowest index on ties.
        if ((s & 7) == 7) {
            const int cbase = ch * 512 + (s >> 3) * 128;
#pragma unroll
            for (int j = 0; j < 8; ++j) {
                const int code = cbase + 8 * tx + j;
                const float e2 = ws[WS_E2 + code];
#pragma unroll
                for (int i = 0; i < 8; ++i) {
                    float dist = __fsub_rn(__fadd_rn(sxr[i], e2), __fmul_rn(2.0f, acc[i][j]));
                    if (dist < bestd[i]) { bestd[i] = dist; bestidx[i] = code; }
                }
            }
        }
    }

    // Cross-thread argmin reduction (16 candidates per row), lexicographic
    // (dist, idx), then exact cross-block combine via u64 atomicMin
    // (dist >= ~130 > 0, so IEEE bit order == numeric order).
    __syncthreads();
    float* rd = smem;                   // [128][16]
    int* ri = (int*)(smem + 2048);      // [128][16]
#pragma unroll
    for (int i = 0; i < 8; ++i) {
        rd[(8 * ty + i) * 16 + tx] = bestd[i];
        ri[(8 * ty + i) * 16 + tx] = bestidx[i];
    }
    __syncthreads();
    if (tid < 128) {
        float bd = rd[tid * 16];
        int bi = ri[tid * 16];
#pragma unroll
        for (int x = 1; x < 16; ++x) {
            float d = rd[tid * 16 + x];
            int ix = ri[tid * 16 + x];
            if (d < bd || (d == bd && ix < bi)) { bd = d; bi = ix; }
        }
        unsigned long long key =
            ((unsigned long long)__float_as_uint(bd) << 32) | (unsigned int)bi;
        atomicMin(&best[row0 + tid], key);
    }

    // ---- last-arriver fused epilogue ----
    __threadfence();
    __syncthreads();
    int* sflag = (int*)(smem + 5000);   // scratch word, clear of q/idx regions
    if (tid == 0) {
        int old = __hip_atomic_fetch_add(&cnt[rowTile], 1, __ATOMIC_ACQ_REL,
                                         __HIP_MEMORY_SCOPE_AGENT);
        *sflag = old;
    }
    __syncthreads();
    if (*sflag == 0) return;            // first arriver: partner will finish
    __threadfence();                    // acquire side

    int* idx_lds = (int*)(smem + 4800); // [128]; q uses smem[0..4735]
    if (tid < 128) {
        unsigned long long v = __hip_atomic_load(&best[row0 + tid], __ATOMIC_RELAXED,
                                                 __HIP_MEMORY_SCOPE_AGENT);
        int bi = (int)(unsigned int)(v & 0xFFFFFFFFull);
        idx_lds[tid] = bi;
        out[IDX_OFF + b * TT + t0 + tid] = (float)bi;  // indices as fp32 values
    }
    __syncthreads();

    // gather(emb, idx) -> [B][D][T] + loss partials (identical structure to R0/R2)
    float lsum = 0.0f;
    float* q = smem;                    // [128][37] (pad 37 breaks bank conflicts)
    const int qr = tid >> 3;            // 0..31 (+32*it)
    const int qf = tid & 7;
    const int er_ = tid & 127;
    const int ed_ = tid >> 7;
    for (int dc = 0; dc < 8; ++dc) {
        const int d0 = dc * 32;
        __syncthreads();
#pragma unroll
        for (int it = 0; it < 4; ++it) {
            int r = qr + 32 * it;
            float4 v = *(const float4*)&emb[(size_t)idx_lds[r] * DIM + d0 + qf * 4];
            float* dst = &q[r * 37 + qf * 4];
            dst[0] = v.x; dst[1] = v.y; dst[2] = v.z; dst[3] = v.w;
        }
        __syncthreads();
#pragma unroll
        for (int k = 0; k < 16; ++k) {
            int dd = ed_ + 2 * k;
            float qq = q[er_ * 37 + dd];
            size_t gaddr = (size_t)b * (DIM * TT) + (size_t)(d0 + dd) * TT + t0 + er_;
            float xx = in[gaddr];
            out[gaddr] = qq;
            float df = __fsub_rn(qq, xx);
            lsum = __fmaf_rn(df, df, lsum);
        }
    }
    // wave reduce + one atomic per wave
#pragma unroll
    for (int off = 32; off > 0; off >>= 1) lsum += __shfl_down(lsum, off, 64);
    if ((tid & 63) == 0) atomicAdd(wloss, lsum);

    // last finisher of all 512 finalizes the loss
    __threadfence();
    __syncthreads();
    if (tid == 0) {
        int old2 = __hip_atomic_fetch_add(&cnt[512], 1, __ATOMIC_ACQ_REL,
                                          __HIP_MEMORY_SCOPE_AGENT);
        if (old2 == 511) {
            __threadfence();
            float L = __hip_atomic_load(wloss, __ATOMIC_RELAXED,
                                        __HIP_MEMORY_SCOPE_AGENT);
            out[LOSS_OFF] = 1.25f * L / 16777216.0f;
        }
    }
}

extern "C" void kernel_launch(void* const* d_in, const int* in_sizes, int n_in,
                              void* d_out, int out_size, void* d_ws, size_t ws_size,
                              hipStream_t stream) {
    const float* in = (const float*)d_in[0];
    const float* emb = (const float*)d_in[1];
    float* out = (float*)d_out;
    float* ws = (float*)d_ws;
    unsigned long long* best = (unsigned long long*)(ws + WS_BEST);
    int* cnt = (int*)(ws + WS_CNT);

    hipLaunchKernelGGL(k_prep_e2, dim3(4), dim3(256), 0, stream, emb, ws);
    hipLaunchKernelGGL(k_prep_sx, dim3(256), dim3(256), 0, stream, in, ws);
    hipLaunchKernelGGL(k_main, dim3(1024), dim3(256), 0, stream, in, emb, ws,
                       best, cnt, ws + WS_LOSS, out);
}

// Round 7
// 1122.351 us; speedup vs baseline: 5.7512x; 5.5559x over previous
//
#include <hip/hip_runtime.h>
#include <math.h>

// Problem constants
#define K_CODES 1024
#define DIM 256
#define BB 32
#define TT 2048
#define NROWS (BB * TT)            // 65536
#define QN (BB * DIM * TT)         // 16777216
#define LOSS_OFF QN
#define IDX_OFF (QN + 1)

// ws layout (in floats)
#define WS_E2 0
#define WS_SX 1024
#define WS_LOSS (1024 + NROWS)     // 66560
#define WS_BEST (WS_LOSS + 2)      // 66562; u64[NROWS] = 2*NROWS floats
#define WS_CNT (WS_BEST + 2 * NROWS)  // 197634; int[513]: 512 rowTile arrivals + 1 done2

// numpy pairwise_sum replica for 256 elements of squares.
__device__ __forceinline__ float pw128_sq(const float* p, int stride) {
    float r[8];
#pragma unroll
    for (int j = 0; j < 8; ++j) {
        float v = p[j * stride];
        r[j] = __fmul_rn(v, v);
    }
#pragma unroll
    for (int i = 8; i < 128; i += 8) {
#pragma unroll
        for (int j = 0; j < 8; ++j) {
            float v = p[(i + j) * stride];
            r[j] = __fadd_rn(r[j], __fmul_rn(v, v));
        }
    }
    return __fadd_rn(__fadd_rn(__fadd_rn(r[0], r[1]), __fadd_rn(r[2], r[3])),
                     __fadd_rn(__fadd_rn(r[4], r[5]), __fadd_rn(r[6], r[7])));
}

__device__ __forceinline__ float pw256_sq(const float* p, int stride) {
    return __fadd_rn(pw128_sq(p, stride), pw128_sq(p + 128 * stride, stride));
}

// async global->LDS 16B copy; LDS dest is wave-uniform base + lane*16.
__device__ __forceinline__ void gload_lds16(const float* g, float* l) {
    __builtin_amdgcn_global_load_lds(
        (const __attribute__((address_space(1))) void*)g,
        (__attribute__((address_space(3))) void*)l, 16, 0, 0);
}

// Kernel 1a: codebook norms + zero loss accumulator + zero arrival counters.
__global__ void k_prep_e2(const float* __restrict__ emb, float* __restrict__ ws) {
    int k = blockIdx.x * 256 + threadIdx.x;
    if (k == 0) ws[WS_LOSS] = 0.0f;
    if (k < 513) ((int*)(ws + WS_CNT))[k] = 0;
    if (k < K_CODES) ws[WS_E2 + k] = pw256_sq(emb + (size_t)k * DIM, 1);
}

// Kernel 1b: per-row squared norms of x + init the argmin keys.
__global__ void k_prep_sx(const float* __restrict__ in, float* __restrict__ ws) {
    int row = blockIdx.x * 256 + threadIdx.x;
    int b = row >> 11;
    int t = row & (TT - 1);
    ws[WS_SX + row] = pw256_sq(in + (size_t)b * (DIM * TT) + t, TT);
    ((unsigned long long*)(ws + WS_BEST))[row] = 0xFFFFFFFFFFFFFFFFull;
}

// Kernel 2: distance GEMM + argmin + fused epilogue.
// Grid 1024: bid = (rowTile<<1)|codeHalf. Each block: 128 rows x 512 codes.
// REGISTER-FREE async pipeline: BOTH tiles staged via global_load_lds into a
// double-buffered 64KB LDS, one barrier per stage. Loads for stage s+1 issue
// right after the top barrier of stage s; the compiler's vmcnt(0) drain before
// the next barrier is the arrival guarantee. No staging registers -> register
// demand is back to R2's serial shape (~108 VGPR, proven spill-free). R5/R6
// lesson: reg-staged pipelining (xr/er live across the 2048-FMA compute)
// forces demand >128 arch VGPRs and the allocator spills to scratch (12 GB
// write traffic, 10x slowdown) no matter what launch_bounds/waves_per_eu says.
//   x-tile: COLUMN-MAJOR xs_cm[c][r] (c=0..31 d-offset, r=0..127 row). Column
//     data is contiguous in global [d][t] layout -> lane l reads 16B at
//     (d0+c)*TT + 4*(l&31), 2 columns per instr, coalesced, linear LDS dest.
//     Compute reads 4 rows per b128 (rows adjacent in column-major); banks
//     (8ty+4u)&31 -> 2-way max (free), no swizzle needed.
//   e-tile: row-major, XOR-swizzled storage via PRE-SWIZZLED global source
//     (R6-verified, bank conflicts 2.09e7 -> 2.2e6).
// Chunk order per (row,code) stays ascending c4, ascending k -> bit-identical
// distances vs R2. Epilogue fused via last-arriver tickets (R5/R6-verified).
__launch_bounds__(256, 2)
__global__ void k_main(const float* __restrict__ in, const float* __restrict__ emb,
                       const float* __restrict__ ws,
                       unsigned long long* __restrict__ best,
                       int* __restrict__ cnt, float* __restrict__ wloss,
                       float* __restrict__ out) {
    __shared__ float smem[16384];      // 64KB: buf0 = xs|es, buf1 = xs|es (8192 floats each)

    const int tid = threadIdx.x;
    // 8x8 wave-internal logical mapping: each wave spans 8 tx x 8 ty.
    const int tx = ((tid >> 6) & 1) * 8 + (tid & 7);
    const int ty = ((tid >> 7) & 1) * 8 + ((tid >> 3) & 7);
    const int wv = tid >> 6;           // wave id
    const int lane = tid & 63;
    const int rowTile = blockIdx.x >> 1;
    const int ch = blockIdx.x & 1;       // code half: codes [ch*512, ch*512+512)
    const int row0 = rowTile * 128;
    const int b = row0 >> 11;            // row0 / 2048
    const int t0 = row0 & (TT - 1);
    const float* xbase = in + (size_t)b * (DIM * TT) + t0;   // + d*TT + r

    // preload row norms for my 8 rows
    float sxr[8];
#pragma unroll
    for (int i = 0; i < 8; ++i) sxr[i] = ws[WS_SX + row0 + 8 * ty + i];

    float bestd[8];
    int bestidx[8];
#pragma unroll
    for (int i = 0; i < 8; ++i) { bestd[i] = INFINITY; bestidx[i] = 0; }

    // ---- prologue: async-stage stage 0 into buf0 (drained by first barrier) ----
    {
        float* xs0 = smem;
        float* es0 = smem + 4096;
        // x: column-major, instr m covers columns 2m,2m+1; wave wv does m=4wv+it
#pragma unroll
        for (int it = 0; it < 4; ++it) {
            int m = 4 * wv + it;
            gload_lds16(xbase + (size_t)(2 * m + (lane >> 5)) * TT + 4 * (lane & 31),
                        &xs0[256 * m]);
        }
        // e: pre-swizzled source, linear dest (R6-verified)
        const int cb = ch * 512;
#pragma unroll
        for (int it = 0; it < 4; ++it) {
            int s2 = 256 * it + 64 * wv + lane;
            int code = s2 >> 3;
            int c4s = (s2 & 7) ^ ((s2 >> 6) & 7);
            gload_lds16(&emb[(size_t)(cb + code) * DIM + c4s * 4],
                        &es0[1024 * it + 256 * wv]);
        }
    }

    float acc[8][8];

    // ---- pipelined main loop: 32 stages (cc = s>>3, dc = s&7) ----
    for (int s = 0; s < 32; ++s) {
        __syncthreads();   // drains vmcnt: buf[s&1] staged; buf[(s+1)&1] readers done
        float* xs = smem + (s & 1) * 8192;
        float* es = xs + 4096;

        // issue next-stage async loads into buf[(s+1)&1]; latency hides under compute
        if (s < 31) {
            const int sn = s + 1;
            const int d0 = (sn & 7) * 32;
            float* xs2 = smem + ((s + 1) & 1) * 8192;
            float* es2 = xs2 + 4096;
#pragma unroll
            for (int it = 0; it < 4; ++it) {
                int m = 4 * wv + it;
                gload_lds16(xbase + (size_t)(d0 + 2 * m + (lane >> 5)) * TT + 4 * (lane & 31),
                            &xs2[256 * m]);
            }
            const int cb = ch * 512 + (sn >> 3) * 128;
#pragma unroll
            for (int it = 0; it < 4; ++it) {
                int s2 = 256 * it + 64 * wv + lane;
                int code = s2 >> 3;
                int c4s = (s2 & 7) ^ ((s2 >> 6) & 7);
                gload_lds16(&emb[(size_t)(cb + code) * DIM + d0 + c4s * 4],
                            &es2[1024 * it + 256 * wv]);
            }
        }

        if ((s & 7) == 0) {
#pragma unroll
            for (int i = 0; i < 8; ++i)
#pragma unroll
                for (int j = 0; j < 8; ++j) acc[i][j] = 0.0f;
        }

        // compute from buf[s&1]: strict ascending-d fma chain per (row, code).
        // xq[k][u] = xs_cm[4c4+k][8ty+4u .. +3] (4 rows); component v -> row 8ty+4u+v.
#pragma unroll
        for (int c4 = 0; c4 < 8; ++c4) {
            float4 xq[4][2], ev[8];
            const int ec = (c4 ^ (tx & 7)) * 4;
#pragma unroll
            for (int k = 0; k < 4; ++k)
#pragma unroll
                for (int u = 0; u < 2; ++u)
                    xq[k][u] = *(const float4*)&xs[(4 * c4 + k) * 128 + 8 * ty + 4 * u];
#pragma unroll
            for (int j = 0; j < 8; ++j) ev[j] = *(const float4*)&es[(8 * tx + j) * 32 + ec];
#pragma unroll
            for (int u = 0; u < 2; ++u)
#pragma unroll
                for (int v = 0; v < 4; ++v) {
                    const int i = 4 * u + v;
                    const float x0 = ((const float*)&xq[0][u])[v];
                    const float x1 = ((const float*)&xq[1][u])[v];
                    const float x2 = ((const float*)&xq[2][u])[v];
                    const float x3 = ((const float*)&xq[3][u])[v];
#pragma unroll
                    for (int j = 0; j < 8; ++j) {
                        float a = acc[i][j];
                        a = __fmaf_rn(x0, ev[j].x, a);
                        a = __fmaf_rn(x1, ev[j].y, a);
                        a = __fmaf_rn(x2, ev[j].z, a);
                        a = __fmaf_rn(x3, ev[j].w, a);
                        acc[i][j] = a;
                    }
                }
        }

        // distances at end of each code chunk: dist = fl(fl(sx+e2) - fl(2*dot));
        // ascending-code scan with strict < keeps lowest index on ties.
        if ((s & 7) == 7) {
            const int cbase = ch * 512 + (s >> 3) * 128;
#pragma unroll
            for (int j = 0; j < 8; ++j) {
                const int code = cbase + 8 * tx + j;
                const float e2 = ws[WS_E2 + code];
#pragma unroll
                for (int i = 0; i < 8; ++i) {
                    float dist = __fsub_rn(__fadd_rn(sxr[i], e2), __fmul_rn(2.0f, acc[i][j]));
                    if (dist < bestd[i]) { bestd[i] = dist; bestidx[i] = code; }
                }
            }
        }
    }

    // Cross-thread argmin reduction (16 candidates per row), lexicographic
    // (dist, idx), then exact cross-block combine via u64 atomicMin
    // (dist >= ~130 > 0, so IEEE bit order == numeric order).
    __syncthreads();
    float* rd = smem;                   // [128][16]
    int* ri = (int*)(smem + 2048);      // [128][16]
#pragma unroll
    for (int i = 0; i < 8; ++i) {
        rd[(8 * ty + i) * 16 + tx] = bestd[i];
        ri[(8 * ty + i) * 16 + tx] = bestidx[i];
    }
    __syncthreads();
    if (tid < 128) {
        float bd = rd[tid * 16];
        int bi = ri[tid * 16];
#pragma unroll
        for (int x = 1; x < 16; ++x) {
            float d = rd[tid * 16 + x];
            int ix = ri[tid * 16 + x];
            if (d < bd || (d == bd && ix < bi)) { bd = d; bi = ix; }
        }
        unsigned long long key =
            ((unsigned long long)__float_as_uint(bd) << 32) | (unsigned int)bi;
        atomicMin(&best[row0 + tid], key);
    }

    // ---- last-arriver fused epilogue (R5/R6-verified) ----
    __threadfence();
    __syncthreads();
    int* sflag = (int*)(smem + 5000);   // scratch word, clear of q/idx regions
    if (tid == 0) {
        int old = __hip_atomic_fetch_add(&cnt[rowTile], 1, __ATOMIC_ACQ_REL,
                                         __HIP_MEMORY_SCOPE_AGENT);
        *sflag = old;
    }
    __syncthreads();
    if (*sflag == 0) return;            // first arriver: partner will finish
    __threadfence();                    // acquire side

    int* idx_lds = (int*)(smem + 4800); // [128]; q uses smem[0..4735]
    if (tid < 128) {
        unsigned long long v = __hip_atomic_load(&best[row0 + tid], __ATOMIC_RELAXED,
                                                 __HIP_MEMORY_SCOPE_AGENT);
        int bi = (int)(unsigned int)(v & 0xFFFFFFFFull);
        idx_lds[tid] = bi;
        out[IDX_OFF + b * TT + t0 + tid] = (float)bi;  // indices as fp32 values
    }
    __syncthreads();

    // gather(emb, idx) -> [B][D][T] + loss partials (identical structure to R0/R2)
    float lsum = 0.0f;
    float* q = smem;                    // [128][37] (pad 37 breaks bank conflicts)
    const int qr = tid >> 3;            // 0..31 (+32*it)
    const int qf = tid & 7;
    const int er_ = tid & 127;
    const int ed_ = tid >> 7;
    for (int dc = 0; dc < 8; ++dc) {
        const int d0 = dc * 32;
        __syncthreads();
#pragma unroll
        for (int it = 0; it < 4; ++it) {
            int r = qr + 32 * it;
            float4 v = *(const float4*)&emb[(size_t)idx_lds[r] * DIM + d0 + qf * 4];
            float* dst = &q[r * 37 + qf * 4];
            dst[0] = v.x; dst[1] = v.y; dst[2] = v.z; dst[3] = v.w;
        }
        __syncthreads();
#pragma unroll
        for (int k = 0; k < 16; ++k) {
            int dd = ed_ + 2 * k;
            float qq = q[er_ * 37 + dd];
            size_t gaddr = (size_t)b * (DIM * TT) + (size_t)(d0 + dd) * TT + t0 + er_;
            float xx = in[gaddr];
            out[gaddr] = qq;
            float df = __fsub_rn(qq, xx);
            lsum = __fmaf_rn(df, df, lsum);
        }
    }
    // wave reduce + one atomic per wave
#pragma unroll
    for (int off = 32; off > 0; off >>= 1) lsum += __shfl_down(lsum, off, 64);
    if ((tid & 63) == 0) atomicAdd(wloss, lsum);

    // last finisher of all 512 finalizes the loss
    __threadfence();
    __syncthreads();
    if (tid == 0) {
        int old2 = __hip_atomic_fetch_add(&cnt[512], 1, __ATOMIC_ACQ_REL,
                                          __HIP_MEMORY_SCOPE_AGENT);
        if (old2 == 511) {
            __threadfence();
            float L = __hip_atomic_load(wloss, __ATOMIC_RELAXED,
                                        __HIP_MEMORY_SCOPE_AGENT);
            out[LOSS_OFF] = 1.25f * L / 16777216.0f;
        }
    }
}

extern "C" void kernel_launch(void* const* d_in, const int* in_sizes, int n_in,
                              void* d_out, int out_size, void* d_ws, size_t ws_size,
                              hipStream_t stream) {
    const float* in = (const float*)d_in[0];
    const float* emb = (const float*)d_in[1];
    float* out = (float*)d_out;
    float* ws = (float*)d_ws;
    unsigned long long* best = (unsigned long long*)(ws + WS_BEST);
    int* cnt = (int*)(ws + WS_CNT);

    hipLaunchKernelGGL(k_prep_e2, dim3(4), dim3(256), 0, stream, emb, ws);
    hipLaunchKernelGGL(k_prep_sx, dim3(256), dim3(256), 0, stream, in, ws);
    hipLaunchKernelGGL(k_main, dim3(1024), dim3(256), 0, stream, in, emb, ws,
                       best, cnt, ws + WS_LOSS, out);
}

// Round 8
// 927.568 us; speedup vs baseline: 6.9589x; 1.2100x over previous
//
#include <hip/hip_runtime.h>
#include <math.h>

// Problem constants
#define K_CODES 1024
#define DIM 256
#define BB 32
#define TT 2048
#define NROWS (BB * TT)            // 65536
#define QN (BB * DIM * TT)         // 16777216
#define LOSS_OFF QN
#define IDX_OFF (QN + 1)

// ws layout (in floats)
#define WS_E2 0
#define WS_SX 1024
#define WS_LOSS (1024 + NROWS)     // 66560
#define WS_BEST (WS_LOSS + 2)      // 66562; u64[NROWS] = 2*NROWS floats
#define WS_CNT (WS_BEST + 2 * NROWS)  // 197634; int[513]: 512 rowTile arrivals + 1 done2

// numpy pairwise_sum replica for 256 elements of squares.
__device__ __forceinline__ float pw128_sq(const float* p, int stride) {
    float r[8];
#pragma unroll
    for (int j = 0; j < 8; ++j) {
        float v = p[j * stride];
        r[j] = __fmul_rn(v, v);
    }
#pragma unroll
    for (int i = 8; i < 128; i += 8) {
#pragma unroll
        for (int j = 0; j < 8; ++j) {
            float v = p[(i + j) * stride];
            r[j] = __fadd_rn(r[j], __fmul_rn(v, v));
        }
    }
    return __fadd_rn(__fadd_rn(__fadd_rn(r[0], r[1]), __fadd_rn(r[2], r[3])),
                     __fadd_rn(__fadd_rn(r[4], r[5]), __fadd_rn(r[6], r[7])));
}

__device__ __forceinline__ float pw256_sq(const float* p, int stride) {
    return __fadd_rn(pw128_sq(p, stride), pw128_sq(p + 128 * stride, stride));
}

// async global->LDS 16B copy; LDS dest is wave-uniform base + lane*16.
__device__ __forceinline__ void gload_lds16(const float* g, float* l) {
    __builtin_amdgcn_global_load_lds(
        (const __attribute__((address_space(1))) void*)g,
        (__attribute__((address_space(3))) void*)l, 16, 0, 0);
}

// Kernel 1a: codebook norms + zero loss accumulator + zero arrival counters.
__global__ void k_prep_e2(const float* __restrict__ emb, float* __restrict__ ws) {
    int k = blockIdx.x * 256 + threadIdx.x;
    if (k == 0) ws[WS_LOSS] = 0.0f;
    if (k < 513) ((int*)(ws + WS_CNT))[k] = 0;
    if (k < K_CODES) ws[WS_E2 + k] = pw256_sq(emb + (size_t)k * DIM, 1);
}

// Kernel 1b: per-row squared norms of x + init the argmin keys.
__global__ void k_prep_sx(const float* __restrict__ in, float* __restrict__ ws) {
    int row = blockIdx.x * 256 + threadIdx.x;
    int b = row >> 11;
    int t = row & (TT - 1);
    ws[WS_SX + row] = pw256_sq(in + (size_t)b * (DIM * TT) + t, TT);
    ((unsigned long long*)(ws + WS_BEST))[row] = 0xFFFFFFFFFFFFFFFFull;
}

// Kernel 2: distance GEMM + argmin + fused epilogue.
// Grid 1024: bid = (rowTile<<1)|codeHalf. Each block: 128 rows x 512 codes.
// STRUCTURE = R2's proven SERIAL 2-barrier loop (108 VGPR, zero spill — the
// only structure the allocator tolerates; every pipelined variant R5/R6/R7
// spilled and/or hit the compiler's vmcnt(0)-before-ds_read drain because the
// two LDS buffers alias). Single 32KB buffer. Plus three individually-proven
// wins:
//  1. e-tile staged via async global_load_lds with PRE-SWIZZLED global source
//     (linear LDS dest; R6/R7-verified: conflicts 3.55e7 -> 2.2e6, bit-exact).
//     No e registers, no e ds_writes; the drain before the 2nd barrier is the
//     arrival guarantee (m97 structure).
//  2. 8x8 wave-internal (tx,ty) remap: each wave spans 8 tx x 8 ty, so xv/ev
//     ds_read_b128 hit 8 disjoint bank-quads (conflict-free); same
//     (row,code)<->thread bijection -> bit-identical distances.
//  3. Fused last-arriver epilogue (R5-R7-verified): 2nd block of each rowTile
//     pair does gather+transpose+loss; 512th finisher writes the final loss.
__launch_bounds__(256, 2)
__global__ void k_main(const float* __restrict__ in, const float* __restrict__ emb,
                       const float* __restrict__ ws,
                       unsigned long long* __restrict__ best,
                       int* __restrict__ cnt, float* __restrict__ wloss,
                       float* __restrict__ out) {
    __shared__ float smem[8192];       // 32KB: xs[4096] | es[4096]; reused by epilogue
    float* xs = smem;
    float* es = smem + 4096;

    const int tid = threadIdx.x;
    // 8x8 wave-internal logical mapping: each wave spans 8 tx x 8 ty.
    const int tx = ((tid >> 6) & 1) * 8 + (tid & 7);
    const int ty = ((tid >> 7) & 1) * 8 + ((tid >> 3) & 7);
    const int wv = tid >> 6;           // wave id
    const int lane = tid & 63;
    const int rowTile = blockIdx.x >> 1;
    const int ch = blockIdx.x & 1;       // code half: codes [ch*512, ch*512+512)
    const int row0 = rowTile * 128;
    const int b = row0 >> 11;            // row0 / 2048
    const int t0 = row0 & (TT - 1);
    const float* xbase = in + (size_t)b * (DIM * TT) + t0;   // + d*TT + r

    // preload row norms for my 8 rows
    float sxr[8];
#pragma unroll
    for (int i = 0; i < 8; ++i) sxr[i] = ws[WS_SX + row0 + 8 * ty + i];

    float bestd[8];
    int bestidx[8];
#pragma unroll
    for (int i = 0; i < 8; ++i) { bestd[i] = INFINITY; bestidx[i] = 0; }

    // x-stage lane mapping (consecutive-8-lane groups span rows 8 apart ->
    // conflict-free swizzled ds_write_b128; global address set per instr is
    // still 64 consecutive floats -> coalesced).
    const int lr = ((tid & 7) << 3) | ((tid >> 3) & 7) | (tid & 64);
    const int lh = tid >> 7;    // x-load half (c4 parity)

    for (int cc = 0; cc < 4; ++cc) {
        const int cbase = ch * 512 + cc * 128;
        float acc[8][8];
#pragma unroll
        for (int i = 0; i < 8; ++i)
#pragma unroll
            for (int j = 0; j < 8; ++j) acc[i][j] = 0.0f;

        for (int dc = 0; dc < 8; ++dc) {
            const int d0 = dc * 32;
            __syncthreads();           // previous stage's readers are done
            // x: reg loads first (so the x ds_write's vmcnt wait tolerates the
            // e gload_lds issued after them staying in flight)
            float xv0[4], xv1[4], xv2[4], xv3[4];
#pragma unroll
            for (int k = 0; k < 4; ++k) xv0[k] = xbase[(size_t)(d0 + 4 * (lh + 0) + k) * TT + lr];
#pragma unroll
            for (int k = 0; k < 4; ++k) xv1[k] = xbase[(size_t)(d0 + 4 * (lh + 2) + k) * TT + lr];
#pragma unroll
            for (int k = 0; k < 4; ++k) xv2[k] = xbase[(size_t)(d0 + 4 * (lh + 4) + k) * TT + lr];
#pragma unroll
            for (int k = 0; k < 4; ++k) xv3[k] = xbase[(size_t)(d0 + 4 * (lh + 6) + k) * TT + lr];
            // e: async direct-to-LDS, pre-swizzled source, linear dest.
            // dest float = s2*4+k = code*32 + cs_lin*4 + k; source chunk
            // c4 = cs_lin ^ ((code>>3)&7)  -> stored layout identical to the
            // swizzled ds_write version -> compute bit-identical.
#pragma unroll
            for (int it = 0; it < 4; ++it) {
                int s2 = 256 * it + 64 * wv + lane;
                int code = s2 >> 3;
                int c4s = (s2 & 7) ^ ((s2 >> 6) & 7);
                gload_lds16(&emb[(size_t)(cbase + code) * DIM + d0 + c4s * 4],
                            &es[1024 * it + 256 * wv]);
            }
            // x: swizzled ds_writes (conflict-free via lr permutation)
            {
                int rbase = lr * 32;
                int sw = (lr >> 3) & 7;
                *(float4*)&xs[rbase + ((lh + 0) ^ sw) * 4] = make_float4(xv0[0], xv0[1], xv0[2], xv0[3]);
                *(float4*)&xs[rbase + ((lh + 2) ^ sw) * 4] = make_float4(xv1[0], xv1[1], xv1[2], xv1[3]);
                *(float4*)&xs[rbase + ((lh + 4) ^ sw) * 4] = make_float4(xv2[0], xv2[1], xv2[2], xv2[3]);
                *(float4*)&xs[rbase + ((lh + 6) ^ sw) * 4] = make_float4(xv3[0], xv3[1], xv3[2], xv3[3]);
            }
            __syncthreads();           // drains vmcnt (e arrival) + lgkm (x writes)

            // compute: strict ascending-d fma chain per (row, code) accumulator.
#pragma unroll
            for (int c4 = 0; c4 < 8; ++c4) {
                float4 xv[8], ev[8];
                const int xc = (c4 ^ (ty & 7)) * 4;
                const int ec = (c4 ^ (tx & 7)) * 4;
#pragma unroll
                for (int i = 0; i < 8; ++i) xv[i] = *(const float4*)&xs[(8 * ty + i) * 32 + xc];
#pragma unroll
                for (int j = 0; j < 8; ++j) ev[j] = *(const float4*)&es[(8 * tx + j) * 32 + ec];
#pragma unroll
                for (int i = 0; i < 8; ++i)
#pragma unroll
                    for (int j = 0; j < 8; ++j) {
                        float a = acc[i][j];
                        a = __fmaf_rn(xv[i].x, ev[j].x, a);
                        a = __fmaf_rn(xv[i].y, ev[j].y, a);
                        a = __fmaf_rn(xv[i].z, ev[j].z, a);
                        a = __fmaf_rn(xv[i].w, ev[j].w, a);
                        acc[i][j] = a;
                    }
            }
        }
        // distances: dist = fl(fl(sx+e2) - fl(2*dot)); ascending-code scan with
        // strict < keeps lowest index on exact ties.
#pragma unroll
        for (int j = 0; j < 8; ++j) {
            const int code = cbase + 8 * tx + j;
            const float e2 = ws[WS_E2 + code];
#pragma unroll
            for (int i = 0; i < 8; ++i) {
                float dist = __fsub_rn(__fadd_rn(sxr[i], e2), __fmul_rn(2.0f, acc[i][j]));
                if (dist < bestd[i]) { bestd[i] = dist; bestidx[i] = code; }
            }
        }
    }

    // Cross-thread argmin reduction (16 candidates per row), lexicographic
    // (dist, idx), then exact cross-block combine via u64 atomicMin
    // (dist >= ~130 > 0, so IEEE bit order == numeric order).
    __syncthreads();
    float* rd = smem;                   // [128][16]
    int* ri = (int*)(smem + 2048);      // [128][16]
#pragma unroll
    for (int i = 0; i < 8; ++i) {
        rd[(8 * ty + i) * 16 + tx] = bestd[i];
        ri[(8 * ty + i) * 16 + tx] = bestidx[i];
    }
    __syncthreads();
    if (tid < 128) {
        float bd = rd[tid * 16];
        int bi = ri[tid * 16];
#pragma unroll
        for (int x = 1; x < 16; ++x) {
            float d = rd[tid * 16 + x];
            int ix = ri[tid * 16 + x];
            if (d < bd || (d == bd && ix < bi)) { bd = d; bi = ix; }
        }
        unsigned long long key =
            ((unsigned long long)__float_as_uint(bd) << 32) | (unsigned int)bi;
        atomicMin(&best[row0 + tid], key);
    }

    // ---- last-arriver fused epilogue (R5-R7-verified) ----
    __threadfence();
    __syncthreads();
    int* sflag = (int*)(smem + 5000);   // scratch word, clear of q/idx regions
    if (tid == 0) {
        int old = __hip_atomic_fetch_add(&cnt[rowTile], 1, __ATOMIC_ACQ_REL,
                                         __HIP_MEMORY_SCOPE_AGENT);
        *sflag = old;
    }
    __syncthreads();
    if (*sflag == 0) return;            // first arriver: partner will finish
    __threadfence();                    // acquire side

    int* idx_lds = (int*)(smem + 4800); // [128]; q uses smem[0..4735]
    if (tid < 128) {
        unsigned long long v = __hip_atomic_load(&best[row0 + tid], __ATOMIC_RELAXED,
                                                 __HIP_MEMORY_SCOPE_AGENT);
        int bi = (int)(unsigned int)(v & 0xFFFFFFFFull);
        idx_lds[tid] = bi;
        out[IDX_OFF + b * TT + t0 + tid] = (float)bi;  // indices as fp32 values
    }
    __syncthreads();

    // gather(emb, idx) -> [B][D][T] + loss partials (identical structure to R0/R2)
    float lsum = 0.0f;
    float* q = smem;                    // [128][37] (pad 37 breaks bank conflicts)
    const int qr = tid >> 3;            // 0..31 (+32*it)
    const int qf = tid & 7;
    const int er_ = tid & 127;
    const int ed_ = tid >> 7;
    for (int dc = 0; dc < 8; ++dc) {
        const int d0 = dc * 32;
        __syncthreads();
#pragma unroll
        for (int it = 0; it < 4; ++it) {
            int r = qr + 32 * it;
            float4 v = *(const float4*)&emb[(size_t)idx_lds[r] * DIM + d0 + qf * 4];
            float* dst = &q[r * 37 + qf * 4];
            dst[0] = v.x; dst[1] = v.y; dst[2] = v.z; dst[3] = v.w;
        }
        __syncthreads();
#pragma unroll
        for (int k = 0; k < 16; ++k) {
            int dd = ed_ + 2 * k;
            float qq = q[er_ * 37 + dd];
            size_t gaddr = (size_t)b * (DIM * TT) + (size_t)(d0 + dd) * TT + t0 + er_;
            float xx = in[gaddr];
            out[gaddr] = qq;
            float df = __fsub_rn(qq, xx);
            lsum = __fmaf_rn(df, df, lsum);
        }
    }
    // wave reduce + one atomic per wave
#pragma unroll
    for (int off = 32; off > 0; off >>= 1) lsum += __shfl_down(lsum, off, 64);
    if ((tid & 63) == 0) atomicAdd(wloss, lsum);

    // last finisher of all 512 finalizes the loss
    __threadfence();
    __syncthreads();
    if (tid == 0) {
        int old2 = __hip_atomic_fetch_add(&cnt[512], 1, __ATOMIC_ACQ_REL,
                                          __HIP_MEMORY_SCOPE_AGENT);
        if (old2 == 511) {
            __threadfence();
            float L = __hip_atomic_load(wloss, __ATOMIC_RELAXED,
                                        __HIP_MEMORY_SCOPE_AGENT);
            out[LOSS_OFF] = 1.25f * L / 16777216.0f;
        }
    }
}

extern "C" void kernel_launch(void* const* d_in, const int* in_sizes, int n_in,
                              void* d_out, int out_size, void* d_ws, size_t ws_size,
                              hipStream_t stream) {
    const float* in = (const float*)d_in[0];
    const float* emb = (const float*)d_in[1];
    float* out = (float*)d_out;
    float* ws = (float*)d_ws;
    unsigned long long* best = (unsigned long long*)(ws + WS_BEST);
    int* cnt = (int*)(ws + WS_CNT);

    hipLaunchKernelGGL(k_prep_e2, dim3(4), dim3(256), 0, stream, emb, ws);
    hipLaunchKernelGGL(k_prep_sx, dim3(256), dim3(256), 0, stream, in, ws);
    hipLaunchKernelGGL(k_main, dim3(1024), dim3(256), 0, stream, in, emb, ws,
                       best, cnt, ws + WS_LOSS, out);
}

// Round 9
// 922.258 us; speedup vs baseline: 6.9989x; 1.0058x over previous
//
#include <hip/hip_runtime.h>
#include <math.h>

// Problem constants
#define K_CODES 1024
#define DIM 256
#define BB 32
#define TT 2048
#define NROWS (BB * TT)            // 65536
#define QN (BB * DIM * TT)         // 16777216
#define LOSS_OFF QN
#define IDX_OFF (QN + 1)

// ws layout (in floats)
#define WS_E2 0
#define WS_SX 1024
#define WS_LOSS (1024 + NROWS)     // 66560
#define WS_BEST (WS_LOSS + 2)      // 66562; u64[NROWS] = 2*NROWS floats
#define WS_CNT (WS_BEST + 2 * NROWS)  // 197634; int[513]: 512 rowTile arrivals + 1 done2

// numpy pairwise_sum replica for 256 elements of squares.
__device__ __forceinline__ float pw128_sq(const float* p, int stride) {
    float r[8];
#pragma unroll
    for (int j = 0; j < 8; ++j) {
        float v = p[j * stride];
        r[j] = __fmul_rn(v, v);
    }
#pragma unroll
    for (int i = 8; i < 128; i += 8) {
#pragma unroll
        for (int j = 0; j < 8; ++j) {
            float v = p[(i + j) * stride];
            r[j] = __fadd_rn(r[j], __fmul_rn(v, v));
        }
    }
    return __fadd_rn(__fadd_rn(__fadd_rn(r[0], r[1]), __fadd_rn(r[2], r[3])),
                     __fadd_rn(__fadd_rn(r[4], r[5]), __fadd_rn(r[6], r[7])));
}

__device__ __forceinline__ float pw256_sq(const float* p, int stride) {
    return __fadd_rn(pw128_sq(p, stride), pw128_sq(p + 128 * stride, stride));
}

// Kernel 1a: codebook norms + zero loss accumulator + zero arrival counters.
__global__ void k_prep_e2(const float* __restrict__ emb, float* __restrict__ ws) {
    int k = blockIdx.x * 256 + threadIdx.x;
    if (k == 0) ws[WS_LOSS] = 0.0f;
    if (k < 513) ((int*)(ws + WS_CNT))[k] = 0;
    if (k < K_CODES) ws[WS_E2 + k] = pw256_sq(emb + (size_t)k * DIM, 1);
}

// Kernel 1b: per-row squared norms of x + init the argmin keys.
__global__ void k_prep_sx(const float* __restrict__ in, float* __restrict__ ws) {
    int row = blockIdx.x * 256 + threadIdx.x;
    int b = row >> 11;
    int t = row & (TT - 1);
    ws[WS_SX + row] = pw256_sq(in + (size_t)b * (DIM * TT) + t, TT);
    ((unsigned long long*)(ws + WS_BEST))[row] = 0xFFFFFFFFFFFFFFFFull;
}

// Kernel 2: distance GEMM + argmin + fused epilogue.
// Grid 1024: bid = (rowTile<<1)|codeHalf. Each block: 128 rows x 512 codes.
// STAGING = R2's exact serial reg+ds_write path for BOTH tiles — the ONLY
// structure that ran at 532 us / 108 VGPR / zero spill. Evidence ledger:
//   - reg-staged pipelining (R5): allocator refuses >128 VGPR -> 12GB spill.
//   - global_load_lds for e (R6/R7/R8): +200-300us stall vs ds_write in this
//     mixed structure (R8 = R2+remap+epi+gload was 818 vs 532). Reverted.
// Deltas vs R2, both bit-exact-proven in R8:
//   1. 8x8 wave-internal (tx,ty) remap: wave spans 8 tx x 8 ty, so xv/ev
//      ds_read_b128 each hit 8 disjoint bank-quads -> conflict-free (R2's
//      3.55e7 conflict cycles came from 16 tx sharing 8 swizzle groups).
//      Same (row,code)<->thread bijection -> bit-identical distances.
//   2. Fused last-arriver epilogue: 2nd block of each rowTile pair does
//      gather+transpose+loss; 512th finisher writes the final loss. Removes
//      the separate k_epi launch + best[] round trip (~120us of R2's total).
__launch_bounds__(256, 2)
__global__ void k_main(const float* __restrict__ in, const float* __restrict__ emb,
                       const float* __restrict__ ws,
                       unsigned long long* __restrict__ best,
                       int* __restrict__ cnt, float* __restrict__ wloss,
                       float* __restrict__ out) {
    __shared__ float smem[8192];       // 32KB: xs[4096] | es[4096]; reused by epilogue
    float* xs = smem;
    float* es = smem + 4096;

    const int tid = threadIdx.x;
    // 8x8 wave-internal logical mapping: each wave spans 8 tx x 8 ty.
    const int tx = ((tid >> 6) & 1) * 8 + (tid & 7);
    const int ty = ((tid >> 7) & 1) * 8 + ((tid >> 3) & 7);
    const int rowTile = blockIdx.x >> 1;
    const int ch = blockIdx.x & 1;       // code half: codes [ch*512, ch*512+512)
    const int row0 = rowTile * 128;
    const int b = row0 >> 11;            // row0 / 2048
    const int t0 = row0 & (TT - 1);
    const float* xbase = in + (size_t)b * (DIM * TT) + t0;   // + d*TT + r

    // preload row norms for my 8 rows
    float sxr[8];
#pragma unroll
    for (int i = 0; i < 8; ++i) sxr[i] = ws[WS_SX + row0 + 8 * ty + i];

    float bestd[8];
    int bestidx[8];
#pragma unroll
    for (int i = 0; i < 8; ++i) { bestd[i] = INFINITY; bestidx[i] = 0; }

    // x-stage lane mapping (consecutive-8-lane groups span rows 8 apart ->
    // conflict-free swizzled ds_write_b128; global address set per instr is
    // still 64 consecutive floats -> coalesced).
    const int lr = ((tid & 7) << 3) | ((tid >> 3) & 7) | (tid & 64);
    const int lh = tid >> 7;    // x-load half (c4 parity)

    for (int cc = 0; cc < 4; ++cc) {
        const int cbase = ch * 512 + cc * 128;
        float acc[8][8];
#pragma unroll
        for (int i = 0; i < 8; ++i)
#pragma unroll
            for (int j = 0; j < 8; ++j) acc[i][j] = 0.0f;

        for (int dc = 0; dc < 8; ++dc) {
            const int d0 = dc * 32;
            __syncthreads();
            // Stage x chunk (R2-exact): logical xs[r][c] = in[b][d0+c][t0+r].
            // XOR-swizzled float4 chunks: chunk c4 of row r at c4 ^ ((r>>3)&7).
#pragma unroll
            for (int it = 0; it < 4; ++it) {
                int c4 = lh + 2 * it;
                float v0 = xbase[(size_t)(d0 + 4 * c4 + 0) * TT + lr];
                float v1 = xbase[(size_t)(d0 + 4 * c4 + 1) * TT + lr];
                float v2 = xbase[(size_t)(d0 + 4 * c4 + 2) * TT + lr];
                float v3 = xbase[(size_t)(d0 + 4 * c4 + 3) * TT + lr];
                int cs = c4 ^ ((lr >> 3) & 7);
                *(float4*)&xs[lr * 32 + cs * 4] = make_float4(v0, v1, v2, v3);
            }
            // Stage e chunk (R2-exact): es[code][c] = emb[cbase+code][d0+c],
            // same swizzle. (8 consecutive lanes = same code, distinct c4 ->
            // distinct banks: clean.)
#pragma unroll
            for (int it = 0; it < 4; ++it) {
                int s = tid + 256 * it;
                int code = s >> 3;
                int c4 = s & 7;
                float4 v = *(const float4*)&emb[(size_t)(cbase + code) * DIM + d0 + c4 * 4];
                int cs = c4 ^ ((code >> 3) & 7);
                *(float4*)&es[code * 32 + cs * 4] = v;
            }
            __syncthreads();
            // compute: strict ascending-d fma chain per (row, code) accumulator.
#pragma unroll
            for (int c4 = 0; c4 < 8; ++c4) {
                float4 xv[8], ev[8];
                const int xc = (c4 ^ (ty & 7)) * 4;
                const int ec = (c4 ^ (tx & 7)) * 4;
#pragma unroll
                for (int i = 0; i < 8; ++i) xv[i] = *(const float4*)&xs[(8 * ty + i) * 32 + xc];
#pragma unroll
                for (int j = 0; j < 8; ++j) ev[j] = *(const float4*)&es[(8 * tx + j) * 32 + ec];
#pragma unroll
                for (int i = 0; i < 8; ++i)
#pragma unroll
                    for (int j = 0; j < 8; ++j) {
                        float a = acc[i][j];
                        a = __fmaf_rn(xv[i].x, ev[j].x, a);
                        a = __fmaf_rn(xv[i].y, ev[j].y, a);
                        a = __fmaf_rn(xv[i].z, ev[j].z, a);
                        a = __fmaf_rn(xv[i].w, ev[j].w, a);
                        acc[i][j] = a;
                    }
            }
        }
        // distances: dist = fl(fl(sx+e2) - fl(2*dot)); ascending-code scan with
        // strict < keeps lowest index on exact ties.
#pragma unroll
        for (int j = 0; j < 8; ++j) {
            const int code = cbase + 8 * tx + j;
            const float e2 = ws[WS_E2 + code];
#pragma unroll
            for (int i = 0; i < 8; ++i) {
                float dist = __fsub_rn(__fadd_rn(sxr[i], e2), __fmul_rn(2.0f, acc[i][j]));
                if (dist < bestd[i]) { bestd[i] = dist; bestidx[i] = code; }
            }
        }
    }

    // Cross-thread argmin reduction (16 candidates per row), lexicographic
    // (dist, idx), then exact cross-block combine via u64 atomicMin
    // (dist >= ~130 > 0, so IEEE bit order == numeric order).
    __syncthreads();
    float* rd = smem;                   // [128][16]
    int* ri = (int*)(smem + 2048);      // [128][16]
#pragma unroll
    for (int i = 0; i < 8; ++i) {
        rd[(8 * ty + i) * 16 + tx] = bestd[i];
        ri[(8 * ty + i) * 16 + tx] = bestidx[i];
    }
    __syncthreads();
    if (tid < 128) {
        float bd = rd[tid * 16];
        int bi = ri[tid * 16];
#pragma unroll
        for (int x = 1; x < 16; ++x) {
            float d = rd[tid * 16 + x];
            int ix = ri[tid * 16 + x];
            if (d < bd || (d == bd && ix < bi)) { bd = d; bi = ix; }
        }
        unsigned long long key =
            ((unsigned long long)__float_as_uint(bd) << 32) | (unsigned int)bi;
        atomicMin(&best[row0 + tid], key);
    }

    // ---- last-arriver fused epilogue (R5-R8-verified) ----
    __threadfence();
    __syncthreads();
    int* sflag = (int*)(smem + 5000);   // scratch word, clear of q/idx regions
    if (tid == 0) {
        int old = __hip_atomic_fetch_add(&cnt[rowTile], 1, __ATOMIC_ACQ_REL,
                                         __HIP_MEMORY_SCOPE_AGENT);
        *sflag = old;
    }
    __syncthreads();
    if (*sflag == 0) return;            // first arriver: partner will finish
    __threadfence();                    // acquire side

    int* idx_lds = (int*)(smem + 4800); // [128]; q uses smem[0..4735]
    if (tid < 128) {
        unsigned long long v = __hip_atomic_load(&best[row0 + tid], __ATOMIC_RELAXED,
                                                 __HIP_MEMORY_SCOPE_AGENT);
        int bi = (int)(unsigned int)(v & 0xFFFFFFFFull);
        idx_lds[tid] = bi;
        out[IDX_OFF + b * TT + t0 + tid] = (float)bi;  // indices as fp32 values
    }
    __syncthreads();

    // gather(emb, idx) -> [B][D][T] + loss partials (identical structure to R0/R2)
    float lsum = 0.0f;
    float* q = smem;                    // [128][37] (pad 37 breaks bank conflicts)
    const int qr = tid >> 3;            // 0..31 (+32*it)
    const int qf = tid & 7;
    const int er_ = tid & 127;
    const int ed_ = tid >> 7;
    for (int dc = 0; dc < 8; ++dc) {
        const int d0 = dc * 32;
        __syncthreads();
#pragma unroll
        for (int it = 0; it < 4; ++it) {
            int r = qr + 32 * it;
            float4 v = *(const float4*)&emb[(size_t)idx_lds[r] * DIM + d0 + qf * 4];
            float* dst = &q[r * 37 + qf * 4];
            dst[0] = v.x; dst[1] = v.y; dst[2] = v.z; dst[3] = v.w;
        }
        __syncthreads();
#pragma unroll
        for (int k = 0; k < 16; ++k) {
            int dd = ed_ + 2 * k;
            float qq = q[er_ * 37 + dd];
            size_t gaddr = (size_t)b * (DIM * TT) + (size_t)(d0 + dd) * TT + t0 + er_;
            float xx = in[gaddr];
            out[gaddr] = qq;
            float df = __fsub_rn(qq, xx);
            lsum = __fmaf_rn(df, df, lsum);
        }
    }
    // wave reduce + one atomic per wave
#pragma unroll
    for (int off = 32; off > 0; off >>= 1) lsum += __shfl_down(lsum, off, 64);
    if ((tid & 63) == 0) atomicAdd(wloss, lsum);

    // last finisher of all 512 finalizes the loss
    __threadfence();
    __syncthreads();
    if (tid == 0) {
        int old2 = __hip_atomic_fetch_add(&cnt[512], 1, __ATOMIC_ACQ_REL,
                                          __HIP_MEMORY_SCOPE_AGENT);
        if (old2 == 511) {
            __threadfence();
            float L = __hip_atomic_load(wloss, __ATOMIC_RELAXED,
                                        __HIP_MEMORY_SCOPE_AGENT);
            out[LOSS_OFF] = 1.25f * L / 16777216.0f;
        }
    }
}

extern "C" void kernel_launch(void* const* d_in, const int* in_sizes, int n_in,
                              void* d_out, int out_size, void* d_ws, size_t ws_size,
                              hipStream_t stream) {
    const float* in = (const float*)d_in[0];
    const float* emb = (const float*)d_in[1];
    float* out = (float*)d_out;
    float* ws = (float*)d_ws;
    unsigned long long* best = (unsigned long long*)(ws + WS_BEST);
    int* cnt = (int*)(ws + WS_CNT);

    hipLaunchKernelGGL(k_prep_e2, dim3(4), dim3(256), 0, stream, emb, ws);
    hipLaunchKernelGGL(k_prep_sx, dim3(256), dim3(256), 0, stream, in, ws);
    hipLaunchKernelGGL(k_main, dim3(1024), dim3(256), 0, stream, in, emb, ws,
                       best, cnt, ws + WS_LOSS, out);
}

// Round 10
// 606.308 us; speedup vs baseline: 10.6461x; 1.5211x over previous
//
#include <hip/hip_runtime.h>
#include <math.h>

// Problem constants
#define K_CODES 1024
#define DIM 256
#define BB 32
#define TT 2048
#define NROWS (BB * TT)            // 65536
#define QN (BB * DIM * TT)         // 16777216
#define LOSS_OFF QN
#define IDX_OFF (QN + 1)

// ws layout (in floats)
#define WS_E2 0
#define WS_SX 1024
#define WS_LOSS (1024 + NROWS)

// numpy pairwise_sum replica for 256 elements of squares:
// S256 = S128(a[0:128]) + S128(a[128:256]); S128 = 8-accumulator unrolled,
// combined as ((r0+r1)+(r2+r3)) + ((r4+r5)+(r6+r7)). All ops forced rn.
__device__ __forceinline__ float pw128_sq(const float* p, int stride) {
    float r[8];
#pragma unroll
    for (int j = 0; j < 8; ++j) {
        float v = p[j * stride];
        r[j] = __fmul_rn(v, v);
    }
#pragma unroll
    for (int i = 8; i < 128; i += 8) {
#pragma unroll
        for (int j = 0; j < 8; ++j) {
            float v = p[(i + j) * stride];
            r[j] = __fadd_rn(r[j], __fmul_rn(v, v));
        }
    }
    return __fadd_rn(__fadd_rn(__fadd_rn(r[0], r[1]), __fadd_rn(r[2], r[3])),
                     __fadd_rn(__fadd_rn(r[4], r[5]), __fadd_rn(r[6], r[7])));
}

__device__ __forceinline__ float pw256_sq(const float* p, int stride) {
    return __fadd_rn(pw128_sq(p, stride), pw128_sq(p + 128 * stride, stride));
}

// Kernel 1a: codebook squared norms (numpy-pairwise) + zero the loss accumulator.
__global__ void k_prep_e2(const float* __restrict__ emb, float* __restrict__ ws) {
    int k = blockIdx.x * 256 + threadIdx.x;
    if (k == 0) ws[WS_LOSS] = 0.0f;
    if (k < K_CODES) ws[WS_E2 + k] = pw256_sq(emb + (size_t)k * DIM, 1);
}

// Kernel 1b: per-row squared norms of x (numpy-pairwise). Row n=(b,t): x[d]=in[b][d][t].
__global__ void k_prep_sx(const float* __restrict__ in, float* __restrict__ ws) {
    int row = blockIdx.x * 256 + threadIdx.x;
    int b = row >> 11;
    int t = row & (TT - 1);
    ws[WS_SX + row] = pw256_sq(in + (size_t)b * (DIM * TT) + t, TT);
}

// Kernel 2: distance GEMM + argmin + gather + transpose write + loss partials.
// STRUCTURE = R0's proven best (562us k_main / 625 total): grid 512, each block
// owns 128 rows x ALL 1024 codes, inline epilogue, NO cross-block machinery.
// Evidence ledger for the structure choice:
//   - R1/R5: reg pressure >128 -> allocator spills to scratch (up to 12GB).
//   - R6/R7: async global_load_lds pipelines -> compiler vmcnt(0) drain before
//     ds_reads (aliasing LDS buffers), 2-10x slower.
//   - R8/R9: ticketed cross-block fused epilogue (threadfence release/acquire =
//     per-XCD L2 writeback+invalidate x 1024 blocks) -> +280us stall vs R2.
// SINGLE delta vs R0 (bit-exact-proven in R8/R9): 8x8 wave-internal (tx,ty)
// remap — each wave spans 8 tx x 8 ty instead of 16 tx x 4 ty, so xv and ev
// ds_read_b128 each hit 8 disjoint bank-quads (conflict-free; R0's 6.39e7
// conflict cycles came from lanes tx and tx+8 sharing swizzle groups). The
// (tx,ty)<->(row,code) bijection over 256 threads is unchanged -> distances,
// argmin scan order, and every fma chain are bit-identical.
__launch_bounds__(256, 2)
__global__ void k_main(const float* __restrict__ in, const float* __restrict__ emb,
                       const float* __restrict__ ws, float* __restrict__ wloss,
                       float* __restrict__ out) {
    __shared__ float smem[8192];       // xs[128*32] | es[128*32]; reused for reduce & q staging
    __shared__ int idx_lds[128];
    float* xs = smem;
    float* es = smem + 4096;

    const int tid = threadIdx.x;
    // 8x8 wave-internal logical mapping (the one change vs R0):
    const int tx = ((tid >> 6) & 1) * 8 + (tid & 7);
    const int ty = ((tid >> 7) & 1) * 8 + ((tid >> 3) & 7);
    const int row0 = blockIdx.x * 128;
    const int b = row0 >> 11;          // row0 / 2048
    const int t0 = row0 & (TT - 1);
    const float* xbase = in + (size_t)b * (DIM * TT) + t0;   // + d*TT + r

    // preload row norms for my 8 rows
    float sxr[8];
#pragma unroll
    for (int i = 0; i < 8; ++i) sxr[i] = ws[WS_SX + row0 + 8 * ty + i];

    float bestd[8];
    int bestidx[8];
#pragma unroll
    for (int i = 0; i < 8; ++i) { bestd[i] = INFINITY; bestidx[i] = 0; }

    const int lr = tid & 127;   // x-load row
    const int lh = tid >> 7;    // x-load half (c4 parity)

    for (int cc = 0; cc < 8; ++cc) {
        const int cbase = cc * 128;
        float acc[8][8];
#pragma unroll
        for (int i = 0; i < 8; ++i)
#pragma unroll
            for (int j = 0; j < 8; ++j) acc[i][j] = 0.0f;

        for (int dc = 0; dc < 8; ++dc) {
            const int d0 = dc * 32;
            __syncthreads();
            // Stage x chunk: logical xs[r][c] = in[b][d0+c][t0+r], c=0..31.
            // XOR-swizzled float4 chunks: chunk c4 of row r stored at c4 ^ ((r>>3)&7).
#pragma unroll
            for (int it = 0; it < 4; ++it) {
                int c4 = lh + 2 * it;
                float v0 = xbase[(size_t)(d0 + 4 * c4 + 0) * TT + lr];
                float v1 = xbase[(size_t)(d0 + 4 * c4 + 1) * TT + lr];
                float v2 = xbase[(size_t)(d0 + 4 * c4 + 2) * TT + lr];
                float v3 = xbase[(size_t)(d0 + 4 * c4 + 3) * TT + lr];
                int cs = c4 ^ ((lr >> 3) & 7);
                *(float4*)&xs[lr * 32 + cs * 4] = make_float4(v0, v1, v2, v3);
            }
            // Stage e chunk: es[code][c] = emb[cbase+code][d0+c], same swizzle.
#pragma unroll
            for (int it = 0; it < 4; ++it) {
                int s = tid + 256 * it;
                int code = s >> 3;
                int c4 = s & 7;
                float4 v = *(const float4*)&emb[(size_t)(cbase + code) * DIM + d0 + c4 * 4];
                int cs = c4 ^ ((code >> 3) & 7);
                *(float4*)&es[code * 32 + cs * 4] = v;
            }
            __syncthreads();
            // Accumulate: strict ascending-d fma chain per (row, code) accumulator.
#pragma unroll
            for (int c4 = 0; c4 < 8; ++c4) {
                float4 xv[8], ev[8];
                const int xc = (c4 ^ (ty & 7)) * 4;
                const int ec = (c4 ^ (tx & 7)) * 4;
#pragma unroll
                for (int i = 0; i < 8; ++i) xv[i] = *(const float4*)&xs[(8 * ty + i) * 32 + xc];
#pragma unroll
                for (int j = 0; j < 8; ++j) ev[j] = *(const float4*)&es[(8 * tx + j) * 32 + ec];
#pragma unroll
                for (int i = 0; i < 8; ++i)
#pragma unroll
                    for (int j = 0; j < 8; ++j) {
                        float a = acc[i][j];
                        a = __fmaf_rn(xv[i].x, ev[j].x, a);
                        a = __fmaf_rn(xv[i].y, ev[j].y, a);
                        a = __fmaf_rn(xv[i].z, ev[j].z, a);
                        a = __fmaf_rn(xv[i].w, ev[j].w, a);
                        acc[i][j] = a;
                    }
            }
        }
        // Distances for this code chunk. Replicate np expression:
        // dist = fl( fl(sx + e2) - fl(2*dot) ); scan ascending code (j asc per cc asc)
        // with strict < keeps lowest index on exact ties.
#pragma unroll
        for (int j = 0; j < 8; ++j) {
            const int code = cbase + 8 * tx + j;
            const float e2 = ws[WS_E2 + code];
#pragma unroll
            for (int i = 0; i < 8; ++i) {
                float dist = __fsub_rn(__fadd_rn(sxr[i], e2), __fmul_rn(2.0f, acc[i][j]));
                if (dist < bestd[i]) { bestd[i] = dist; bestidx[i] = code; }
            }
        }
    }

    // Cross-thread argmin reduction (16 candidates per row), lexicographic (dist, idx).
    __syncthreads();
    float* rd = smem;                   // [128][16]
    int* ri = (int*)(smem + 2048);      // [128][16]
#pragma unroll
    for (int i = 0; i < 8; ++i) {
        rd[(8 * ty + i) * 16 + tx] = bestd[i];
        ri[(8 * ty + i) * 16 + tx] = bestidx[i];
    }
    __syncthreads();
    if (tid < 128) {
        float bd = rd[tid * 16];
        int bi = ri[tid * 16];
#pragma unroll
        for (int x = 1; x < 16; ++x) {
            float d = rd[tid * 16 + x];
            int ix = ri[tid * 16 + x];
            if (d < bd || (d == bd && ix < bi)) { bd = d; bi = ix; }
        }
        idx_lds[tid] = bi;
        out[IDX_OFF + b * TT + t0 + tid] = (float)bi;  // indices output as fp32 values
    }
    __syncthreads();

    // Epilogue: quantized = gather(emb, idx) written back as [B][D][T]; loss partials.
    float lsum = 0.0f;
    float* q = smem;                    // [128][37] (pad 37 breaks bank conflicts)
    const int qr = tid >> 3;            // 0..31 (+32*it)
    const int qf = tid & 7;
    const int er_ = tid & 127;
    const int ed_ = tid >> 7;
    for (int dc = 0; dc < 8; ++dc) {
        const int d0 = dc * 32;
        __syncthreads();
#pragma unroll
        for (int it = 0; it < 4; ++it) {
            int r = qr + 32 * it;
            float4 v = *(const float4*)&emb[(size_t)idx_lds[r] * DIM + d0 + qf * 4];
            float* dst = &q[r * 37 + qf * 4];
            dst[0] = v.x; dst[1] = v.y; dst[2] = v.z; dst[3] = v.w;
        }
        __syncthreads();
#pragma unroll
        for (int k = 0; k < 16; ++k) {
            int dd = ed_ + 2 * k;
            float qq = q[er_ * 37 + dd];
            size_t gaddr = (size_t)b * (DIM * TT) + (size_t)(d0 + dd) * TT + t0 + er_;
            float xx = in[gaddr];
            out[gaddr] = qq;
            float df = __fsub_rn(qq, xx);
            lsum = __fmaf_rn(df, df, lsum);
        }
    }
    // wave reduce + one atomic per wave
#pragma unroll
    for (int off = 32; off > 0; off >>= 1) lsum += __shfl_down(lsum, off, 64);
    if ((tid & 63) == 0) atomicAdd(wloss, lsum);
}

// Kernel 3: finalize loss = (1 + 0.25) * mean((q - x)^2)
__global__ void k_loss(const float* __restrict__ wloss, float* __restrict__ out) {
    out[LOSS_OFF] = 1.25f * wloss[0] / 16777216.0f;
}

extern "C" void kernel_launch(void* const* d_in, const int* in_sizes, int n_in,
                              void* d_out, int out_size, void* d_ws, size_t ws_size,
                              hipStream_t stream) {
    const float* in = (const float*)d_in[0];
    const float* emb = (const float*)d_in[1];
    float* out = (float*)d_out;
    float* ws = (float*)d_ws;

    hipLaunchKernelGGL(k_prep_e2, dim3(4), dim3(256), 0, stream, emb, ws);
    hipLaunchKernelGGL(k_prep_sx, dim3(256), dim3(256), 0, stream, in, ws);
    hipLaunchKernelGGL(k_main, dim3(512), dim3(256), 0, stream, in, emb, ws,
                       ws + WS_LOSS, out);
    hipLaunchKernelGGL(k_loss, dim3(1), dim3(1), 0, stream, ws + WS_LOSS, out);
}